// Round 6
// baseline (28202.966 us; speedup 1.0000x reference)
//
#include <hip/hip_runtime.h>
#include <math.h>

#define SEQ 4096
#define DIM 256
#define HIDD 512
#define HH 256
#define G4 1024      // 4*H
#define TT 12
#define AA 128
#define START_TAG 10
#define STOP_TAG 11
#define NEGV (-10000.0f)
#define NG 4         // workgroups per direction
#define SL 64        // h-slice per workgroup (256/NG)
#define NC 64        // CRF chunks
#define CL 64        // CRF chunk length

typedef unsigned int u32;
typedef unsigned long long u64;

__device__ __forceinline__ float sigf(float x){ return 1.0f/(1.0f+__expf(-x)); }
__device__ __forceinline__ float tanhfast(float x){ float e=__expf(2.f*x); return (e-1.f)/(e+1.f); }

// ---- prep: transpose-pack Wih (2,G4,K) f32 -> float4 [2][K/4][G4] (coalesced j)
template<int K>
__global__ __launch_bounds__(256) void pack_wih(const float* __restrict__ src, float4* __restrict__ dst){
  const int KQ = K/4;
  int idx = blockIdx.x*256 + threadIdx.x;        // 2*KQ*G4 total
  int j = idx & (G4-1);
  int r = idx >> 10;
  int k4 = r % KQ;
  int d  = r / KQ;
  const float* p = src + ((size_t)(d*G4 + j))*K + k4*4;
  dst[idx] = make_float4(p[0],p[1],p[2],p[3]);
}

__global__ __launch_bounds__(64) void gather_embed(const int* __restrict__ sent, const float* __restrict__ embed,
                                                   float4* __restrict__ x4){
  int s = blockIdx.x;
  const float4* src = (const float4*)(embed + (size_t)sent[s]*DIM);
  x4[(size_t)s*64 + threadIdx.x] = src[threadIdx.x];
}

// ---- input projection: P[d][t][j] = b[d][j] + sum_k in[t][k]*Wih[d][j][k]
template<int K>
__global__ __launch_bounds__(256) void inproj(const float* __restrict__ in, const float4* __restrict__ WT4,
                                              const float* __restrict__ bias, float* __restrict__ P){
  const int KQ = K/4;
  int bid = blockIdx.x;             // 2 * 256 * 4 blocks
  int jt = bid & 3;
  int st = (bid>>2) & 255;
  int d  = bid >> 10;
  __shared__ float4 xs[16*KQ];
  int tid = threadIdx.x;
  int s0 = st*16;
  const float4* in4 = (const float4*)(in + (size_t)s0*K);
  for (int i=tid; i<16*KQ; i+=256) xs[i] = in4[i];
  __syncthreads();
  int j = jt*256 + tid;
  float b = bias[d*G4 + j];
  float acc[16];
  #pragma unroll
  for (int r=0;r<16;r++) acc[r]=b;
  const float4* w = WT4 + (size_t)d*KQ*G4 + j;
  for (int k4=0;k4<KQ;k4++){
    float4 wv = w[(size_t)k4*G4];
    #pragma unroll
    for (int r=0;r<16;r++){
      float4 xv = xs[r*KQ + k4];
      acc[r] = fmaf(wv.x,xv.x, fmaf(wv.y,xv.y, fmaf(wv.z,xv.z, fmaf(wv.w,xv.w, acc[r]))));
    }
  }
  #pragma unroll
  for (int r=0;r<16;r++)
    P[((size_t)d*SEQ + (s0+r))*G4 + j] = acc[r];
}

// ---- LSTM scan v5: weights STRUCTURALLY resident in AGPRs (explicit
//      v_accvgpr_read per use; init loads get accvgpr_write copies).
//      Tagged uint64 ring exchange unchanged.
#define WLD(i) float4 w##i = wp[i];
#define WDOT(i) { float4 hv = hs4[i]; float a0_,a1_,a2_,a3_; \
  asm volatile("v_accvgpr_read_b32 %0, %1" : "=v"(a0_) : "a"(w##i.x)); \
  asm volatile("v_accvgpr_read_b32 %0, %1" : "=v"(a1_) : "a"(w##i.y)); \
  asm volatile("v_accvgpr_read_b32 %0, %1" : "=v"(a2_) : "a"(w##i.z)); \
  asm volatile("v_accvgpr_read_b32 %0, %1" : "=v"(a3_) : "a"(w##i.w)); \
  acc = fmaf(a0_,hv.x, fmaf(a1_,hv.y, fmaf(a2_,hv.z, fmaf(a3_,hv.w, acc)))); }

__global__ __launch_bounds__(256,1) void lstm_scan5(const float* __restrict__ Whh,
                                                    const float* __restrict__ P,
                                                    float* __restrict__ hout,
                                                    u64* __restrict__ exbase){
  const int d = blockIdx.x & 1;
  const int g = blockIdx.x >> 1;
  const int tid = threadIdx.x;
  const int q  = tid >> 6;              // gate index (i,f,g,o)
  const int jj = tid & 63;              // index within h-slice
  const int j  = q*256 + g*SL + jj;     // global gate-row
  __shared__ float4 hs4[64];            // h_{t-1} (256 f32)
  __shared__ float gv[256];             // gate pre-activations for this WG
  float* hs = (float*)hs4;

  const float4* wp = (const float4*)(Whh + ((size_t)(d*G4 + j))*HH);
  WLD(0) WLD(1) WLD(2) WLD(3) WLD(4) WLD(5) WLD(6) WLD(7)
  WLD(8) WLD(9) WLD(10) WLD(11) WLD(12) WLD(13) WLD(14) WLD(15)
  WLD(16) WLD(17) WLD(18) WLD(19) WLD(20) WLD(21) WLD(22) WLD(23)
  WLD(24) WLD(25) WLD(26) WLD(27) WLD(28) WLD(29) WLD(30) WLD(31)
  WLD(32) WLD(33) WLD(34) WLD(35) WLD(36) WLD(37) WLD(38) WLD(39)
  WLD(40) WLD(41) WLD(42) WLD(43) WLD(44) WLD(45) WLD(46) WLD(47)
  WLD(48) WLD(49) WLD(50) WLD(51) WLD(52) WLD(53) WLD(54) WLD(55)
  WLD(56) WLD(57) WLD(58) WLD(59) WLD(60) WLD(61) WLD(62) WLD(63)

  hs[tid] = 0.f;
  float c = 0.f;
  const float* Pd = P + (size_t)d*SEQ*G4;
  const int t0 = d ? SEQ-1 : 0;
  float pcur = Pd[(size_t)t0*G4 + j];
  u64* exd = exbase + (size_t)d*1024;   // [4 slots][256]
  __syncthreads();

  for (int tt=0; tt<SEQ; ++tt){
    const int t  = d ? (SEQ-1-tt) : tt;
    const int tn = d ? (t>0 ? t-1 : 0) : (t<SEQ-1 ? t+1 : t);
    float pnext = Pd[(size_t)tn*G4 + j];      // prefetch next step's P

    float acc = pcur;
    WDOT(0) WDOT(1) WDOT(2) WDOT(3) WDOT(4) WDOT(5) WDOT(6) WDOT(7)
    WDOT(8) WDOT(9) WDOT(10) WDOT(11) WDOT(12) WDOT(13) WDOT(14) WDOT(15)
    WDOT(16) WDOT(17) WDOT(18) WDOT(19) WDOT(20) WDOT(21) WDOT(22) WDOT(23)
    WDOT(24) WDOT(25) WDOT(26) WDOT(27) WDOT(28) WDOT(29) WDOT(30) WDOT(31)
    WDOT(32) WDOT(33) WDOT(34) WDOT(35) WDOT(36) WDOT(37) WDOT(38) WDOT(39)
    WDOT(40) WDOT(41) WDOT(42) WDOT(43) WDOT(44) WDOT(45) WDOT(46) WDOT(47)
    WDOT(48) WDOT(49) WDOT(50) WDOT(51) WDOT(52) WDOT(53) WDOT(54) WDOT(55)
    WDOT(56) WDOT(57) WDOT(58) WDOT(59) WDOT(60) WDOT(61) WDOT(62) WDOT(63)
    gv[tid] = acc;
    __syncthreads();

    u64* exsl = exd + (size_t)(tt&3)*256;
    if (tid < SL){
      float gi = sigf(gv[tid]);
      float gf = sigf(gv[64 + tid]);
      float gg = tanhfast(gv[128 + tid]);
      float go = sigf(gv[192 + tid]);
      c = gf*c + gi*gg;
      float h = go*tanhfast(c);
      hout[(size_t)t*HIDD + d*HH + g*SL + tid] = h;        // plain store for later kernels
      u64 pk = ((u64)(u32)(tt+1) << 32) | (u64)__float_as_uint(h);
      __hip_atomic_store(&exsl[g*SL + tid], pk, __ATOMIC_RELAXED, __HIP_MEMORY_SCOPE_AGENT);
    }
    // every thread polls its own h element (tag carries readiness)
    const u64 want = (u64)(u32)(tt+1);
    u64 v;
    do {
      v = __hip_atomic_load(&exsl[tid], __ATOMIC_RELAXED, __HIP_MEMORY_SCOPE_AGENT);
    } while ((v>>32) != want);
    hs[tid] = __uint_as_float((u32)v);
    pcur = pnext;
    __syncthreads();
  }
}

// ---- attention scores: scores[s] = v . tanh(Wa h[s] + ba)
__global__ __launch_bounds__(128) void attn_scores(const float* __restrict__ h1, const float* __restrict__ Wa,
                                                   const float* __restrict__ ba, const float* __restrict__ vctx,
                                                   float* __restrict__ scores){
  __shared__ float4 hsl[8*128];
  __shared__ float red[2];
  int tid = threadIdx.x;
  int s0 = blockIdx.x*8;
  const float4* h4 = (const float4*)(h1 + (size_t)s0*HIDD);
  for (int i=tid;i<8*128;i+=128) hsl[i]=h4[i];
  __syncthreads();
  const float4* wa = (const float4*)(Wa + (size_t)tid*HIDD);
  float acc[8];
  #pragma unroll
  for (int r=0;r<8;r++) acc[r]=0.f;
  for (int k4=0;k4<128;k4++){
    float4 wv = wa[k4];
    #pragma unroll
    for (int r=0;r<8;r++){
      float4 xv = hsl[r*128+k4];
      acc[r] = fmaf(wv.x,xv.x,fmaf(wv.y,xv.y,fmaf(wv.z,xv.z,fmaf(wv.w,xv.w,acc[r]))));
    }
  }
  float myb = ba[tid], myv = vctx[tid];
  for (int r=0;r<8;r++){
    float p = tanhf(acc[r]+myb)*myv;
    #pragma unroll
    for (int off=32;off;off>>=1) p += __shfl_down(p, off);
    if ((tid&63)==0) red[tid>>6]=p;
    __syncthreads();
    if (tid==0) scores[s0+r] = red[0]+red[1];
    __syncthreads();
  }
}

__global__ __launch_bounds__(1024) void softmax_seq(const float* __restrict__ scores, float* __restrict__ wsm){
  __shared__ float red[16];
  __shared__ float gsh[2];
  int tid=threadIdx.x;
  float4 v = ((const float4*)scores)[tid];
  float m = fmaxf(fmaxf(v.x,v.y),fmaxf(v.z,v.w));
  #pragma unroll
  for (int off=32;off;off>>=1) m = fmaxf(m, __shfl_down(m,off));
  if ((tid&63)==0) red[tid>>6]=m;
  __syncthreads();
  if (tid==0){ float mm=red[0]; for (int i=1;i<16;i++) mm=fmaxf(mm,red[i]); gsh[0]=mm; }
  __syncthreads();
  float gm = gsh[0];
  float e0=__expf(v.x-gm), e1=__expf(v.y-gm), e2=__expf(v.z-gm), e3=__expf(v.w-gm);
  float s = e0+e1+e2+e3;
  #pragma unroll
  for (int off=32;off;off>>=1) s += __shfl_down(s,off);
  if ((tid&63)==0) red[tid>>6]=s;
  __syncthreads();
  if (tid==0){ float ss=0; for (int i=0;i<16;i++) ss+=red[i]; gsh[1]=ss; }
  __syncthreads();
  float inv = 1.0f/gsh[1];
  ((float4*)wsm)[tid] = make_float4(e0*inv,e1*inv,e2*inv,e3*inv);
}

// ---- MLP emissions: feats = W2 relu(w_s*(W1 h) + b1) + b2
__global__ __launch_bounds__(256) void mlp_feats(const float* __restrict__ h1, const float* __restrict__ wsm,
                                                 const float* __restrict__ W1, const float* __restrict__ b1,
                                                 const float* __restrict__ W2, const float* __restrict__ b2,
                                                 float* __restrict__ feats){
  __shared__ float4 hsl[8*128];
  __shared__ float rl[8][256];
  __shared__ float wloc[8];
  int tid=threadIdx.x;
  int s0=blockIdx.x*8;
  const float4* h4=(const float4*)(h1 + (size_t)s0*HIDD);
  for (int i=tid;i<8*128;i+=256) hsl[i]=h4[i];
  if (tid<8) wloc[tid]=wsm[s0+tid];
  __syncthreads();
  const float4* w1=(const float4*)(W1 + (size_t)tid*HIDD);
  float acc[8];
  #pragma unroll
  for (int r=0;r<8;r++) acc[r]=0.f;
  for (int k4=0;k4<128;k4++){
    float4 wv=w1[k4];
    #pragma unroll
    for (int r=0;r<8;r++){
      float4 xv=hsl[r*128+k4];
      acc[r]=fmaf(wv.x,xv.x,fmaf(wv.y,xv.y,fmaf(wv.z,xv.z,fmaf(wv.w,xv.w,acc[r]))));
    }
  }
  float bb=b1[tid];
  #pragma unroll
  for (int r=0;r<8;r++) rl[r][tid]=fmaxf(fmaf(acc[r],wloc[r],bb),0.f);
  __syncthreads();
  if (tid < 96){
    int r=tid/12, t=tid-12*(tid/12);
    const float* w2=W2 + t*256;
    float a=b2[t];
    for (int m2=0;m2<256;m2++) a += w2[m2]*rl[r][m2];
    feats[(size_t)(s0+r)*TT + t]=a;
  }
}

// ---- CRF parallel scan: chunk products of M_t[i][j] = trans[i][j] + feats[t][i]
__global__ __launch_bounds__(192) void crf_chunks(const float* __restrict__ feats,
                                                  const float* __restrict__ trans,
                                                  float* __restrict__ Cmat){
  int c = blockIdx.x;
  int tid = threadIdx.x;
  __shared__ float trs[144];
  __shared__ float cur[144];
  __shared__ float ft[12];
  if (tid<144) trs[tid]=trans[tid];
  __syncthreads();
  int t0 = c*CL;
  int i = tid/12, jcol = tid - 12*(tid/12);
  float cv = 0.f;
  if (tid<144) cv = trs[tid] + feats[(size_t)t0*TT + i];
  for (int s=t0+1; s<t0+CL; ++s){
    if (tid<144) cur[tid]=cv;
    if (tid<12)  ft[tid] = feats[(size_t)s*TT+tid];
    __syncthreads();
    if (tid<144){
      float v[12]; float m=-3.0e38f;
      #pragma unroll
      for (int k=0;k<12;k++){ v[k] = trs[i*12+k] + cur[k*12+jcol]; m=fmaxf(m,v[k]); }
      float ss=0.f;
      #pragma unroll
      for (int k=0;k<12;k++) ss += __expf(v[k]-m);
      cv = ft[i] + m + __logf(ss);
    }
    __syncthreads();
  }
  if (tid<144) Cmat[(size_t)c*144 + tid] = cv;
}

__global__ __launch_bounds__(256) void crf_combine(const float* __restrict__ Cmat,
                                                   const float* __restrict__ trans,
                                                   const float* __restrict__ feats,
                                                   const int* __restrict__ tags,
                                                   float* __restrict__ out){
  __shared__ float trb[144];
  __shared__ float fv[12];
  __shared__ float Csh[144];
  __shared__ float red[4];
  __shared__ float goldsh;
  int tid=threadIdx.x;
  if (tid<144) trb[tid]=trans[tid];
  __syncthreads();
  float gacc=0.f;
  for (int s=tid; s<SEQ; s+=256){
    int tg = tags[s];
    int pv = s ? tags[s-1] : START_TAG;
    gacc += feats[(size_t)s*TT+tg] + trb[tg*12+pv];
  }
  #pragma unroll
  for (int off=32;off;off>>=1) gacc += __shfl_down(gacc,off);
  if ((tid&63)==0) red[tid>>6]=gacc;
  __syncthreads();
  if (tid==0) goldsh = red[0]+red[1]+red[2]+red[3] + trb[STOP_TAG*12 + tags[SEQ-1]];
  if (tid<12) fv[tid] = (tid==START_TAG) ? 0.f : NEGV;
  __syncthreads();
  for (int cc=0; cc<NC; ++cc){
    if (tid<144) Csh[tid] = Cmat[(size_t)cc*144+tid];
    __syncthreads();
    float nf=0.f;
    if (tid<12){
      float v[12]; float m=-3.0e38f;
      #pragma unroll
      for (int k=0;k<12;k++){ v[k]=Csh[tid*12+k]+fv[k]; m=fmaxf(m,v[k]); }
      float ss=0.f;
      #pragma unroll
      for (int k=0;k<12;k++) ss+=__expf(v[k]-m);
      nf = m+__logf(ss);
    }
    __syncthreads();
    if (tid<12) fv[tid]=nf;
    __syncthreads();
  }
  if (tid==0){
    float v[12]; float m=-3.0e38f;
    #pragma unroll
    for (int k=0;k<12;k++){ v[k]=fv[k]+trb[STOP_TAG*12+k]; m=fmaxf(m,v[k]); }
    float ss=0.f;
    #pragma unroll
    for (int k=0;k<12;k++) ss+=__expf(v[k]-m);
    out[0] = m + __logf(ss) - goldsh;
  }
}

extern "C" void kernel_launch(void* const* d_in, const int* in_sizes, int n_in,
                              void* d_out, int out_size, void* d_ws, size_t ws_size,
                              hipStream_t stream){
  const int*   sent  = (const int*)d_in[0];
  const int*   tags  = (const int*)d_in[1];
  const float* embed = (const float*)d_in[2];
  const float* W0ih  = (const float*)d_in[3];
  const float* W0hh  = (const float*)d_in[4];
  const float* b0    = (const float*)d_in[5];
  const float* W1ih  = (const float*)d_in[6];
  const float* W1hh  = (const float*)d_in[7];
  const float* b1l   = (const float*)d_in[8];
  const float* Wa    = (const float*)d_in[9];
  const float* ba    = (const float*)d_in[10];
  const float* vctx  = (const float*)d_in[11];
  const float* W1m   = (const float*)d_in[12];
  const float* b1m   = (const float*)d_in[13];
  const float* W2m   = (const float*)d_in[14];
  const float* b2m   = (const float*)d_in[15];
  const float* trans = (const float*)d_in[16];
  float* out = (float*)d_out;

  float* ws = (float*)d_ws;
  size_t off = 0;
  float*  x     = ws + off;            off += (size_t)SEQ*DIM;       // 4 MB
  float4* WihT0 = (float4*)(ws + off); off += (size_t)2*64*G4*4;     // 2 MB
  float4* WihT1 = (float4*)(ws + off); off += (size_t)2*128*G4*4;    // 4 MB
  float*  h0    = ws + off;            off += (size_t)SEQ*HIDD;      // 8 MB
  float*  h1    = ws + off;            off += (size_t)SEQ*HIDD;      // 8 MB
  float*  scores= ws + off;            off += SEQ;
  float*  wsm   = ws + off;            off += SEQ;
  float*  feats = ws + off;            off += (size_t)SEQ*TT;
  float*  Cmat  = ws + off;            off += (size_t)NC*144;
  u64*    exch  = (u64*)(ws + off);    off += (size_t)2*2048*2;      // 2 layers * 2048 u64
  float*  P     = ws + off;            off += (size_t)2*SEQ*G4;      // 32 MB

  pack_wih<256><<<dim3(2*64*G4/256), dim3(256), 0, stream>>>(W0ih, WihT0);
  pack_wih<512><<<dim3(2*128*G4/256), dim3(256), 0, stream>>>(W1ih, WihT1);

  gather_embed<<<dim3(SEQ), dim3(64), 0, stream>>>(sent, embed, (float4*)x);

  inproj<256><<<dim3(2048), dim3(256), 0, stream>>>(x, WihT0, b0, P);
  lstm_scan5<<<dim3(2*NG), dim3(256), 0, stream>>>(W0hh, P, h0, exch);
  inproj<512><<<dim3(2048), dim3(256), 0, stream>>>(h0, WihT1, b1l, P);
  lstm_scan5<<<dim3(2*NG), dim3(256), 0, stream>>>(W1hh, P, h1, exch + 2048);

  attn_scores<<<dim3(512), dim3(128), 0, stream>>>(h1, Wa, ba, vctx, scores);
  softmax_seq<<<dim3(1), dim3(1024), 0, stream>>>(scores, wsm);
  mlp_feats<<<dim3(512), dim3(256), 0, stream>>>(h1, wsm, W1m, b1m, W2m, b2m, feats);
  crf_chunks<<<dim3(NC), dim3(192), 0, stream>>>(feats, trans, Cmat);
  crf_combine<<<dim3(1), dim3(256), 0, stream>>>(Cmat, trans, feats, tags, out);
}

// Round 7
// 26377.045 us; speedup vs baseline: 1.0692x; 1.0692x over previous
//
#include <hip/hip_runtime.h>
#include <math.h>

#define SEQ 4096
#define DIM 256
#define HIDD 512
#define HH 256
#define G4 1024      // 4*H
#define TT 12
#define AA 128
#define START_TAG 10
#define STOP_TAG 11
#define NEGV (-10000.0f)
#define NG 4         // workgroups per direction
#define SL 64        // h-slice per workgroup (256/NG)
#define NC 64        // CRF chunks
#define CL 64        // CRF chunk length

typedef unsigned int u32;
typedef unsigned long long u64;

__device__ __forceinline__ float sigf(float x){ return 1.0f/(1.0f+__expf(-x)); }
__device__ __forceinline__ float tanhfast(float x){ float e=__expf(2.f*x); return (e-1.f)/(e+1.f); }

__device__ __forceinline__ unsigned short f2bf(float f){
  u32 u = __float_as_uint(f);
  u32 r = u + 0x7fffu + ((u>>16)&1u);   // RNE
  return (unsigned short)(r>>16);
}

// ---- prep: transpose-pack Wih (2,G4,K) f32 -> float4 [2][K/4][G4] (coalesced j)
template<int K>
__global__ __launch_bounds__(256) void pack_wih(const float* __restrict__ src, float4* __restrict__ dst){
  const int KQ = K/4;
  int idx = blockIdx.x*256 + threadIdx.x;        // 2*KQ*G4 total
  int j = idx & (G4-1);
  int r = idx >> 10;
  int k4 = r % KQ;
  int d  = r / KQ;
  const float* p = src + ((size_t)(d*G4 + j))*K + k4*4;
  dst[idx] = make_float4(p[0],p[1],p[2],p[3]);
}

// ---- prep: pack Whh (2,G4,HH) f32 -> bf16 pairs, uint4 [2][32][G4] (k8-major, coalesced j)
__global__ __launch_bounds__(256) void pack_whh(const float* __restrict__ src, uint4* __restrict__ dst){
  int idx = blockIdx.x*256 + threadIdx.x;        // 65536 total
  int j  = idx & (G4-1);
  int k8 = (idx>>10) & 31;
  int d  = idx >> 15;
  const float* p = src + ((size_t)(d*G4 + j))*HH + k8*8;
  uint4 v;
  v.x = (u32)f2bf(p[0]) | ((u32)f2bf(p[1])<<16);
  v.y = (u32)f2bf(p[2]) | ((u32)f2bf(p[3])<<16);
  v.z = (u32)f2bf(p[4]) | ((u32)f2bf(p[5])<<16);
  v.w = (u32)f2bf(p[6]) | ((u32)f2bf(p[7])<<16);
  dst[idx] = v;
}

__global__ __launch_bounds__(64) void gather_embed(const int* __restrict__ sent, const float* __restrict__ embed,
                                                   float4* __restrict__ x4){
  int s = blockIdx.x;
  const float4* src = (const float4*)(embed + (size_t)sent[s]*DIM);
  x4[(size_t)s*64 + threadIdx.x] = src[threadIdx.x];
}

// ---- input projection: P[d][t][j] = b[d][j] + sum_k in[t][k]*Wih[d][j][k]
template<int K>
__global__ __launch_bounds__(256) void inproj(const float* __restrict__ in, const float4* __restrict__ WT4,
                                              const float* __restrict__ bias, float* __restrict__ P){
  const int KQ = K/4;
  int bid = blockIdx.x;             // 2 * 256 * 4 blocks
  int jt = bid & 3;
  int st = (bid>>2) & 255;
  int d  = bid >> 10;
  __shared__ float4 xs[16*KQ];
  int tid = threadIdx.x;
  int s0 = st*16;
  const float4* in4 = (const float4*)(in + (size_t)s0*K);
  for (int i=tid; i<16*KQ; i+=256) xs[i] = in4[i];
  __syncthreads();
  int j = jt*256 + tid;
  float b = bias[d*G4 + j];
  float acc[16];
  #pragma unroll
  for (int r=0;r<16;r++) acc[r]=b;
  const float4* w = WT4 + (size_t)d*KQ*G4 + j;
  for (int k4=0;k4<KQ;k4++){
    float4 wv = w[(size_t)k4*G4];
    #pragma unroll
    for (int r=0;r<16;r++){
      float4 xv = xs[r*KQ + k4];
      acc[r] = fmaf(wv.x,xv.x, fmaf(wv.y,xv.y, fmaf(wv.z,xv.z, fmaf(wv.w,xv.w, acc[r]))));
    }
  }
  #pragma unroll
  for (int r=0;r<16;r++)
    P[((size_t)d*SEQ + (s0+r))*G4 + j] = acc[r];
}

// ---- LSTM scan v6: bf16-packed weights in 128 named VGPRs (under the 256
//      arch-VGPR cap -> no spill). Unpack via shl/and per use. 4 acc chains.
//      Tagged uint64 ring exchange unchanged.
#define QLD(i) uint4 q##i = wqp[(size_t)(i)*G4]; \
  asm volatile("" : "+v"(q##i.x), "+v"(q##i.y), "+v"(q##i.z), "+v"(q##i.w));
#define QDOT(i,A) { float4 ha = hs4[2*(i)]; float4 hb = hs4[2*(i)+1]; \
  A = fmaf(__uint_as_float(q##i.x<<16),           ha.x, A); \
  A = fmaf(__uint_as_float(q##i.x & 0xffff0000u), ha.y, A); \
  A = fmaf(__uint_as_float(q##i.y<<16),           ha.z, A); \
  A = fmaf(__uint_as_float(q##i.y & 0xffff0000u), ha.w, A); \
  A = fmaf(__uint_as_float(q##i.z<<16),           hb.x, A); \
  A = fmaf(__uint_as_float(q##i.z & 0xffff0000u), hb.y, A); \
  A = fmaf(__uint_as_float(q##i.w<<16),           hb.z, A); \
  A = fmaf(__uint_as_float(q##i.w & 0xffff0000u), hb.w, A); }

__global__ __launch_bounds__(256,1) void lstm_scan6(const uint4* __restrict__ WhhB,
                                                    const float* __restrict__ P,
                                                    float* __restrict__ hout,
                                                    u64* __restrict__ exbase){
  const int d = blockIdx.x & 1;
  const int g = blockIdx.x >> 1;
  const int tid = threadIdx.x;
  const int q  = tid >> 6;              // gate index (i,f,g,o)
  const int jj = tid & 63;              // index within h-slice
  const int j  = q*256 + g*SL + jj;     // global gate-row
  __shared__ float4 hs4[64];            // h_{t-1} (256 f32)
  __shared__ float gv[256];             // gate pre-activations for this WG
  float* hs = (float*)hs4;

  const uint4* wqp = WhhB + (size_t)d*32*G4 + j;
  QLD(0) QLD(1) QLD(2) QLD(3) QLD(4) QLD(5) QLD(6) QLD(7)
  QLD(8) QLD(9) QLD(10) QLD(11) QLD(12) QLD(13) QLD(14) QLD(15)
  QLD(16) QLD(17) QLD(18) QLD(19) QLD(20) QLD(21) QLD(22) QLD(23)
  QLD(24) QLD(25) QLD(26) QLD(27) QLD(28) QLD(29) QLD(30) QLD(31)

  hs[tid] = 0.f;
  float c = 0.f;
  const float* Pd = P + (size_t)d*SEQ*G4;
  const int t0 = d ? SEQ-1 : 0;
  float pcur = Pd[(size_t)t0*G4 + j];
  u64* exd = exbase + (size_t)d*1024;   // [4 slots][256]
  __syncthreads();

  for (int tt=0; tt<SEQ; ++tt){
    const int t  = d ? (SEQ-1-tt) : tt;
    const int tn = d ? (t>0 ? t-1 : 0) : (t<SEQ-1 ? t+1 : t);
    float pnext = Pd[(size_t)tn*G4 + j];      // prefetch next step's P

    float acc0 = pcur, acc1 = 0.f, acc2 = 0.f, acc3 = 0.f;
    QDOT(0,acc0) QDOT(1,acc1) QDOT(2,acc2) QDOT(3,acc3)
    QDOT(4,acc0) QDOT(5,acc1) QDOT(6,acc2) QDOT(7,acc3)
    QDOT(8,acc0) QDOT(9,acc1) QDOT(10,acc2) QDOT(11,acc3)
    QDOT(12,acc0) QDOT(13,acc1) QDOT(14,acc2) QDOT(15,acc3)
    QDOT(16,acc0) QDOT(17,acc1) QDOT(18,acc2) QDOT(19,acc3)
    QDOT(20,acc0) QDOT(21,acc1) QDOT(22,acc2) QDOT(23,acc3)
    QDOT(24,acc0) QDOT(25,acc1) QDOT(26,acc2) QDOT(27,acc3)
    QDOT(28,acc0) QDOT(29,acc1) QDOT(30,acc2) QDOT(31,acc3)
    gv[tid] = (acc0+acc1)+(acc2+acc3);
    __syncthreads();

    u64* exsl = exd + (size_t)(tt&3)*256;
    if (tid < SL){
      float gi = sigf(gv[tid]);
      float gf = sigf(gv[64 + tid]);
      float gg = tanhfast(gv[128 + tid]);
      float go = sigf(gv[192 + tid]);
      c = gf*c + gi*gg;
      float h = go*tanhfast(c);
      hout[(size_t)t*HIDD + d*HH + g*SL + tid] = h;        // plain store for later kernels
      u64 pk = ((u64)(u32)(tt+1) << 32) | (u64)__float_as_uint(h);
      __hip_atomic_store(&exsl[g*SL + tid], pk, __ATOMIC_RELAXED, __HIP_MEMORY_SCOPE_AGENT);
    }
    // every thread polls its own h element (tag carries readiness)
    const u64 want = (u64)(u32)(tt+1);
    u64 v;
    do {
      v = __hip_atomic_load(&exsl[tid], __ATOMIC_RELAXED, __HIP_MEMORY_SCOPE_AGENT);
    } while ((v>>32) != want);
    hs[tid] = __uint_as_float((u32)v);
    pcur = pnext;
    __syncthreads();
  }
}

// ---- attention scores: scores[s] = v . tanh(Wa h[s] + ba)
__global__ __launch_bounds__(128) void attn_scores(const float* __restrict__ h1, const float* __restrict__ Wa,
                                                   const float* __restrict__ ba, const float* __restrict__ vctx,
                                                   float* __restrict__ scores){
  __shared__ float4 hsl[8*128];
  __shared__ float red[2];
  int tid = threadIdx.x;
  int s0 = blockIdx.x*8;
  const float4* h4 = (const float4*)(h1 + (size_t)s0*HIDD);
  for (int i=tid;i<8*128;i+=128) hsl[i]=h4[i];
  __syncthreads();
  const float4* wa = (const float4*)(Wa + (size_t)tid*HIDD);
  float acc[8];
  #pragma unroll
  for (int r=0;r<8;r++) acc[r]=0.f;
  for (int k4=0;k4<128;k4++){
    float4 wv = wa[k4];
    #pragma unroll
    for (int r=0;r<8;r++){
      float4 xv = hsl[r*128+k4];
      acc[r] = fmaf(wv.x,xv.x,fmaf(wv.y,xv.y,fmaf(wv.z,xv.z,fmaf(wv.w,xv.w,acc[r]))));
    }
  }
  float myb = ba[tid], myv = vctx[tid];
  for (int r=0;r<8;r++){
    float p = tanhf(acc[r]+myb)*myv;
    #pragma unroll
    for (int off=32;off;off>>=1) p += __shfl_down(p, off);
    if ((tid&63)==0) red[tid>>6]=p;
    __syncthreads();
    if (tid==0) scores[s0+r] = red[0]+red[1];
    __syncthreads();
  }
}

__global__ __launch_bounds__(1024) void softmax_seq(const float* __restrict__ scores, float* __restrict__ wsm){
  __shared__ float red[16];
  __shared__ float gsh[2];
  int tid=threadIdx.x;
  float4 v = ((const float4*)scores)[tid];
  float m = fmaxf(fmaxf(v.x,v.y),fmaxf(v.z,v.w));
  #pragma unroll
  for (int off=32;off;off>>=1) m = fmaxf(m, __shfl_down(m,off));
  if ((tid&63)==0) red[tid>>6]=m;
  __syncthreads();
  if (tid==0){ float mm=red[0]; for (int i=1;i<16;i++) mm=fmaxf(mm,red[i]); gsh[0]=mm; }
  __syncthreads();
  float gm = gsh[0];
  float e0=__expf(v.x-gm), e1=__expf(v.y-gm), e2=__expf(v.z-gm), e3=__expf(v.w-gm);
  float s = e0+e1+e2+e3;
  #pragma unroll
  for (int off=32;off;off>>=1) s += __shfl_down(s,off);
  if ((tid&63)==0) red[tid>>6]=s;
  __syncthreads();
  if (tid==0){ float ss=0; for (int i=0;i<16;i++) ss+=red[i]; gsh[1]=ss; }
  __syncthreads();
  float inv = 1.0f/gsh[1];
  ((float4*)wsm)[tid] = make_float4(e0*inv,e1*inv,e2*inv,e3*inv);
}

// ---- MLP emissions: feats = W2 relu(w_s*(W1 h) + b1) + b2
__global__ __launch_bounds__(256) void mlp_feats(const float* __restrict__ h1, const float* __restrict__ wsm,
                                                 const float* __restrict__ W1, const float* __restrict__ b1,
                                                 const float* __restrict__ W2, const float* __restrict__ b2,
                                                 float* __restrict__ feats){
  __shared__ float4 hsl[8*128];
  __shared__ float rl[8][256];
  __shared__ float wloc[8];
  int tid=threadIdx.x;
  int s0=blockIdx.x*8;
  const float4* h4=(const float4*)(h1 + (size_t)s0*HIDD);
  for (int i=tid;i<8*128;i+=256) hsl[i]=h4[i];
  if (tid<8) wloc[tid]=wsm[s0+tid];
  __syncthreads();
  const float4* w1=(const float4*)(W1 + (size_t)tid*HIDD);
  float acc[8];
  #pragma unroll
  for (int r=0;r<8;r++) acc[r]=0.f;
  for (int k4=0;k4<128;k4++){
    float4 wv=w1[k4];
    #pragma unroll
    for (int r=0;r<8;r++){
      float4 xv=hsl[r*128+k4];
      acc[r]=fmaf(wv.x,xv.x,fmaf(wv.y,xv.y,fmaf(wv.z,xv.z,fmaf(wv.w,xv.w,acc[r]))));
    }
  }
  float bb=b1[tid];
  #pragma unroll
  for (int r=0;r<8;r++) rl[r][tid]=fmaxf(fmaf(acc[r],wloc[r],bb),0.f);
  __syncthreads();
  if (tid < 96){
    int r=tid/12, t=tid-12*(tid/12);
    const float* w2=W2 + t*256;
    float a=b2[t];
    for (int m2=0;m2<256;m2++) a += w2[m2]*rl[r][m2];
    feats[(size_t)(s0+r)*TT + t]=a;
  }
}

// ---- CRF parallel scan: chunk products of M_t[i][j] = trans[i][j] + feats[t][i]
__global__ __launch_bounds__(192) void crf_chunks(const float* __restrict__ feats,
                                                  const float* __restrict__ trans,
                                                  float* __restrict__ Cmat){
  int c = blockIdx.x;
  int tid = threadIdx.x;
  __shared__ float trs[144];
  __shared__ float cur[144];
  __shared__ float ft[12];
  if (tid<144) trs[tid]=trans[tid];
  __syncthreads();
  int t0 = c*CL;
  int i = tid/12, jcol = tid - 12*(tid/12);
  float cv = 0.f;
  if (tid<144) cv = trs[tid] + feats[(size_t)t0*TT + i];
  for (int s=t0+1; s<t0+CL; ++s){
    if (tid<144) cur[tid]=cv;
    if (tid<12)  ft[tid] = feats[(size_t)s*TT+tid];
    __syncthreads();
    if (tid<144){
      float v[12]; float m=-3.0e38f;
      #pragma unroll
      for (int k=0;k<12;k++){ v[k] = trs[i*12+k] + cur[k*12+jcol]; m=fmaxf(m,v[k]); }
      float ss=0.f;
      #pragma unroll
      for (int k=0;k<12;k++) ss += __expf(v[k]-m);
      cv = ft[i] + m + __logf(ss);
    }
    __syncthreads();
  }
  if (tid<144) Cmat[(size_t)c*144 + tid] = cv;
}

__global__ __launch_bounds__(256) void crf_combine(const float* __restrict__ Cmat,
                                                   const float* __restrict__ trans,
                                                   const float* __restrict__ feats,
                                                   const int* __restrict__ tags,
                                                   float* __restrict__ out){
  __shared__ float trb[144];
  __shared__ float fv[12];
  __shared__ float Csh[144];
  __shared__ float red[4];
  __shared__ float goldsh;
  int tid=threadIdx.x;
  if (tid<144) trb[tid]=trans[tid];
  __syncthreads();
  float gacc=0.f;
  for (int s=tid; s<SEQ; s+=256){
    int tg = tags[s];
    int pv = s ? tags[s-1] : START_TAG;
    gacc += feats[(size_t)s*TT+tg] + trb[tg*12+pv];
  }
  #pragma unroll
  for (int off=32;off;off>>=1) gacc += __shfl_down(gacc,off);
  if ((tid&63)==0) red[tid>>6]=gacc;
  __syncthreads();
  if (tid==0) goldsh = red[0]+red[1]+red[2]+red[3] + trb[STOP_TAG*12 + tags[SEQ-1]];
  if (tid<12) fv[tid] = (tid==START_TAG) ? 0.f : NEGV;
  __syncthreads();
  for (int cc=0; cc<NC; ++cc){
    if (tid<144) Csh[tid] = Cmat[(size_t)cc*144+tid];
    __syncthreads();
    float nf=0.f;
    if (tid<12){
      float v[12]; float m=-3.0e38f;
      #pragma unroll
      for (int k=0;k<12;k++){ v[k]=Csh[tid*12+k]+fv[k]; m=fmaxf(m,v[k]); }
      float ss=0.f;
      #pragma unroll
      for (int k=0;k<12;k++) ss+=__expf(v[k]-m);
      nf = m+__logf(ss);
    }
    __syncthreads();
    if (tid<12) fv[tid]=nf;
    __syncthreads();
  }
  if (tid==0){
    float v[12]; float m=-3.0e38f;
    #pragma unroll
    for (int k=0;k<12;k++){ v[k]=fv[k]+trb[STOP_TAG*12+k]; m=fmaxf(m,v[k]); }
    float ss=0.f;
    #pragma unroll
    for (int k=0;k<12;k++) ss+=__expf(v[k]-m);
    out[0] = m + __logf(ss) - goldsh;
  }
}

extern "C" void kernel_launch(void* const* d_in, const int* in_sizes, int n_in,
                              void* d_out, int out_size, void* d_ws, size_t ws_size,
                              hipStream_t stream){
  const int*   sent  = (const int*)d_in[0];
  const int*   tags  = (const int*)d_in[1];
  const float* embed = (const float*)d_in[2];
  const float* W0ih  = (const float*)d_in[3];
  const float* W0hh  = (const float*)d_in[4];
  const float* b0    = (const float*)d_in[5];
  const float* W1ih  = (const float*)d_in[6];
  const float* W1hh  = (const float*)d_in[7];
  const float* b1l   = (const float*)d_in[8];
  const float* Wa    = (const float*)d_in[9];
  const float* ba    = (const float*)d_in[10];
  const float* vctx  = (const float*)d_in[11];
  const float* W1m   = (const float*)d_in[12];
  const float* b1m   = (const float*)d_in[13];
  const float* W2m   = (const float*)d_in[14];
  const float* b2m   = (const float*)d_in[15];
  const float* trans = (const float*)d_in[16];
  float* out = (float*)d_out;

  float* ws = (float*)d_ws;
  size_t off = 0;
  float*  x     = ws + off;            off += (size_t)SEQ*DIM;       // 4 MB
  float4* WihT0 = (float4*)(ws + off); off += (size_t)2*64*G4*4;     // 2 MB
  float4* WihT1 = (float4*)(ws + off); off += (size_t)2*128*G4*4;    // 4 MB
  uint4*  WhhB0 = (uint4*)(ws + off);  off += (size_t)2*32*G4*4;     // 1 MB
  uint4*  WhhB1 = (uint4*)(ws + off);  off += (size_t)2*32*G4*4;     // 1 MB
  float*  h0    = ws + off;            off += (size_t)SEQ*HIDD;      // 8 MB
  float*  h1    = ws + off;            off += (size_t)SEQ*HIDD;      // 8 MB
  float*  scores= ws + off;            off += SEQ;
  float*  wsm   = ws + off;            off += SEQ;
  float*  feats = ws + off;            off += (size_t)SEQ*TT;
  float*  Cmat  = ws + off;            off += (size_t)NC*144;
  u64*    exch  = (u64*)(ws + off);    off += (size_t)2*2048*2;      // 2 layers * 2048 u64
  float*  P     = ws + off;            off += (size_t)2*SEQ*G4;      // 32 MB

  pack_wih<256><<<dim3(2*64*G4/256), dim3(256), 0, stream>>>(W0ih, WihT0);
  pack_wih<512><<<dim3(2*128*G4/256), dim3(256), 0, stream>>>(W1ih, WihT1);
  pack_whh<<<dim3(2*32*G4/256), dim3(256), 0, stream>>>(W0hh, WhhB0);
  pack_whh<<<dim3(2*32*G4/256), dim3(256), 0, stream>>>(W1hh, WhhB1);

  gather_embed<<<dim3(SEQ), dim3(64), 0, stream>>>(sent, embed, (float4*)x);

  inproj<256><<<dim3(2048), dim3(256), 0, stream>>>(x, WihT0, b0, P);
  lstm_scan6<<<dim3(2*NG), dim3(256), 0, stream>>>(WhhB0, P, h0, exch);
  inproj<512><<<dim3(2048), dim3(256), 0, stream>>>(h0, WihT1, b1l, P);
  lstm_scan6<<<dim3(2*NG), dim3(256), 0, stream>>>(WhhB1, P, h1, exch + 2048);

  attn_scores<<<dim3(512), dim3(128), 0, stream>>>(h1, Wa, ba, vctx, scores);
  softmax_seq<<<dim3(1), dim3(1024), 0, stream>>>(scores, wsm);
  mlp_feats<<<dim3(512), dim3(256), 0, stream>>>(h1, wsm, W1m, b1m, W2m, b2m, feats);
  crf_chunks<<<dim3(NC), dim3(192), 0, stream>>>(feats, trans, Cmat);
  crf_combine<<<dim3(1), dim3(256), 0, stream>>>(Cmat, trans, feats, tags, out);
}

// Round 9
// 24894.177 us; speedup vs baseline: 1.1329x; 1.0596x over previous
//
#include <hip/hip_runtime.h>
#include <math.h>

#define SEQ 4096
#define DIM 256
#define HIDD 512
#define HH 256
#define G4 1024      // 4*H
#define TT 12
#define AA 128
#define START_TAG 10
#define STOP_TAG 11
#define NEGV (-10000.0f)
#define NG 4         // workgroups per direction
#define SL 64        // h-slice per workgroup (256/NG)
#define NC 64        // CRF chunks
#define CL 64        // CRF chunk length

typedef unsigned int u32;
typedef unsigned long long u64;

__device__ __forceinline__ float sigf(float x){ return 1.0f/(1.0f+__expf(-x)); }
__device__ __forceinline__ float tanhfast(float x){ float e=__expf(2.f*x); return (e-1.f)/(e+1.f); }

__device__ __forceinline__ unsigned short f2bf(float f){
  u32 u = __float_as_uint(f);
  u32 r = u + 0x7fffu + ((u>>16)&1u);   // RNE
  return (unsigned short)(r>>16);
}

// ---- prep: transpose-pack Wih (2,G4,K) f32 -> float4 [2][K/4][G4] (coalesced j)
template<int K>
__global__ __launch_bounds__(256) void pack_wih(const float* __restrict__ src, float4* __restrict__ dst){
  const int KQ = K/4;
  int idx = blockIdx.x*256 + threadIdx.x;        // 2*KQ*G4 total
  int j = idx & (G4-1);
  int r = idx >> 10;
  int k4 = r % KQ;
  int d  = r / KQ;
  const float* p = src + ((size_t)(d*G4 + j))*K + k4*4;
  dst[idx] = make_float4(p[0],p[1],p[2],p[3]);
}

// ---- prep: pack Whh (2,G4,HH) f32 -> bf16 pairs, uint4 [2][32][G4] (k8-major, coalesced j)
__global__ __launch_bounds__(256) void pack_whh(const float* __restrict__ src, uint4* __restrict__ dst){
  int idx = blockIdx.x*256 + threadIdx.x;        // 65536 total
  int j  = idx & (G4-1);
  int k8 = (idx>>10) & 31;
  int d  = idx >> 15;
  const float* p = src + ((size_t)(d*G4 + j))*HH + k8*8;
  uint4 v;
  v.x = (u32)f2bf(p[0]) | ((u32)f2bf(p[1])<<16);
  v.y = (u32)f2bf(p[2]) | ((u32)f2bf(p[3])<<16);
  v.z = (u32)f2bf(p[4]) | ((u32)f2bf(p[5])<<16);
  v.w = (u32)f2bf(p[6]) | ((u32)f2bf(p[7])<<16);
  dst[idx] = v;
}

__global__ __launch_bounds__(64) void gather_embed(const int* __restrict__ sent, const float* __restrict__ embed,
                                                   float4* __restrict__ x4){
  int s = blockIdx.x;
  const float4* src = (const float4*)(embed + (size_t)sent[s]*DIM);
  x4[(size_t)s*64 + threadIdx.x] = src[threadIdx.x];
}

// ---- input projection: P[d][t][j] = b[d][j] + sum_k in[t][k]*Wih[d][j][k]
template<int K>
__global__ __launch_bounds__(256) void inproj(const float* __restrict__ in, const float4* __restrict__ WT4,
                                              const float* __restrict__ bias, float* __restrict__ P){
  const int KQ = K/4;
  int bid = blockIdx.x;             // 2 * 256 * 4 blocks
  int jt = bid & 3;
  int st = (bid>>2) & 255;
  int d  = bid >> 10;
  __shared__ float4 xs[16*KQ];
  int tid = threadIdx.x;
  int s0 = st*16;
  const float4* in4 = (const float4*)(in + (size_t)s0*K);
  for (int i=tid; i<16*KQ; i+=256) xs[i] = in4[i];
  __syncthreads();
  int j = jt*256 + tid;
  float b = bias[d*G4 + j];
  float acc[16];
  #pragma unroll
  for (int r=0;r<16;r++) acc[r]=b;
  const float4* w = WT4 + (size_t)d*KQ*G4 + j;
  for (int k4=0;k4<KQ;k4++){
    float4 wv = w[(size_t)k4*G4];
    #pragma unroll
    for (int r=0;r<16;r++){
      float4 xv = xs[r*KQ + k4];
      acc[r] = fmaf(wv.x,xv.x, fmaf(wv.y,xv.y, fmaf(wv.z,xv.z, fmaf(wv.w,xv.w, acc[r]))));
    }
  }
  #pragma unroll
  for (int r=0;r<16;r++)
    P[((size_t)d*SEQ + (s0+r))*G4 + j] = acc[r];
}

// ---- LSTM scan v7: bf16 weights LDS-RESIDENT (128 KB/WG, [k8][local_row]
//      layout -> contiguous conflict-free ds_read_b128). Tagged u64 ring sync.
#define QDOT(i,A) { uint4 qv = wl[(i)*256 + tid]; \
  float4 ha = hs4[2*(i)]; float4 hb = hs4[2*(i)+1]; \
  A = fmaf(__uint_as_float(qv.x<<16),           ha.x, A); \
  A = fmaf(__uint_as_float(qv.x & 0xffff0000u), ha.y, A); \
  A = fmaf(__uint_as_float(qv.y<<16),           ha.z, A); \
  A = fmaf(__uint_as_float(qv.y & 0xffff0000u), ha.w, A); \
  A = fmaf(__uint_as_float(qv.z<<16),           hb.x, A); \
  A = fmaf(__uint_as_float(qv.z & 0xffff0000u), hb.y, A); \
  A = fmaf(__uint_as_float(qv.w<<16),           hb.z, A); \
  A = fmaf(__uint_as_float(qv.w & 0xffff0000u), hb.w, A); }

__global__ __launch_bounds__(256,1) void lstm_scan7(const uint4* __restrict__ WhhB,
                                                    const float* __restrict__ P,
                                                    float* __restrict__ hout,
                                                    u64* __restrict__ exbase){
  extern __shared__ uint4 smem[];
  uint4*  wl  = smem;                         // 32*256 uint4 = 128 KB
  float4* hs4 = (float4*)(wl + 32*256);       // 64 float4 (h_{t-1}, 256 f32)
  float*  gv  = (float*)(hs4 + 64);           // 256 f32 gate pre-activations
  float*  hs  = (float*)hs4;

  const int d = blockIdx.x & 1;
  const int g = blockIdx.x >> 1;
  const int tid = threadIdx.x;
  const int q  = tid >> 6;              // gate index (i,f,g,o)
  const int jj = tid & 63;              // index within h-slice
  const int j  = q*256 + g*SL + jj;     // global gate-row

  // stage weights into LDS once: wl[k8*256 + tid] = WhhB[d][k8][j]
  const uint4* wsrc = WhhB + (size_t)d*32*G4 + j;
  #pragma unroll 4
  for (int k8=0;k8<32;k8++) wl[k8*256 + tid] = wsrc[(size_t)k8*G4];

  hs[tid] = 0.f;
  float c = 0.f;
  const float* Pd = P + (size_t)d*SEQ*G4;
  const int t0 = d ? SEQ-1 : 0;
  float pcur = Pd[(size_t)t0*G4 + j];
  u64* exd = exbase + (size_t)d*1024;   // [4 slots][256]
  __syncthreads();

  for (int tt=0; tt<SEQ; ++tt){
    const int t  = d ? (SEQ-1-tt) : tt;
    const int tn = d ? (t>0 ? t-1 : 0) : (t<SEQ-1 ? t+1 : t);
    float pnext = Pd[(size_t)tn*G4 + j];      // prefetch next step's P

    float acc0 = pcur, acc1 = 0.f, acc2 = 0.f, acc3 = 0.f;
    #pragma unroll
    for (int kk=0; kk<8; ++kk){
      QDOT(kk*4+0,acc0) QDOT(kk*4+1,acc1) QDOT(kk*4+2,acc2) QDOT(kk*4+3,acc3)
    }
    gv[tid] = (acc0+acc1)+(acc2+acc3);
    __syncthreads();

    u64* exsl = exd + (size_t)(tt&3)*256;
    if (tid < SL){
      float gi = sigf(gv[tid]);
      float gf = sigf(gv[64 + tid]);
      float gg = tanhfast(gv[128 + tid]);
      float go = sigf(gv[192 + tid]);
      c = gf*c + gi*gg;
      float h = go*tanhfast(c);
      hout[(size_t)t*HIDD + d*HH + g*SL + tid] = h;        // plain store for later kernels
      u64 pk = ((u64)(u32)(tt+1) << 32) | (u64)__float_as_uint(h);
      __hip_atomic_store(&exsl[g*SL + tid], pk, __ATOMIC_RELAXED, __HIP_MEMORY_SCOPE_AGENT);
    }
    // every thread polls its own h element (tag carries readiness)
    const u64 want = (u64)(u32)(tt+1);
    u64 v;
    do {
      v = __hip_atomic_load(&exsl[tid], __ATOMIC_RELAXED, __HIP_MEMORY_SCOPE_AGENT);
    } while ((v>>32) != want);
    hs[tid] = __uint_as_float((u32)v);
    pcur = pnext;
    __syncthreads();
  }
}

// ---- attention scores: scores[s] = v . tanh(Wa h[s] + ba)
__global__ __launch_bounds__(128) void attn_scores(const float* __restrict__ h1, const float* __restrict__ Wa,
                                                   const float* __restrict__ ba, const float* __restrict__ vctx,
                                                   float* __restrict__ scores){
  __shared__ float4 hsl[8*128];
  __shared__ float red[2];
  int tid = threadIdx.x;
  int s0 = blockIdx.x*8;
  const float4* h4 = (const float4*)(h1 + (size_t)s0*HIDD);
  for (int i=tid;i<8*128;i+=128) hsl[i]=h4[i];
  __syncthreads();
  const float4* wa = (const float4*)(Wa + (size_t)tid*HIDD);
  float acc[8];
  #pragma unroll
  for (int r=0;r<8;r++) acc[r]=0.f;
  for (int k4=0;k4<128;k4++){
    float4 wv = wa[k4];
    #pragma unroll
    for (int r=0;r<8;r++){
      float4 xv = hsl[r*128+k4];
      acc[r] = fmaf(wv.x,xv.x,fmaf(wv.y,xv.y,fmaf(wv.z,xv.z,fmaf(wv.w,xv.w,acc[r]))));
    }
  }
  float myb = ba[tid], myv = vctx[tid];
  for (int r=0;r<8;r++){
    float p = tanhf(acc[r]+myb)*myv;
    #pragma unroll
    for (int off=32;off;off>>=1) p += __shfl_down(p, off);
    if ((tid&63)==0) red[tid>>6]=p;
    __syncthreads();
    if (tid==0) scores[s0+r] = red[0]+red[1];
    __syncthreads();
  }
}

__global__ __launch_bounds__(1024) void softmax_seq(const float* __restrict__ scores, float* __restrict__ wsm){
  __shared__ float red[16];
  __shared__ float gsh[2];
  int tid=threadIdx.x;
  float4 v = ((const float4*)scores)[tid];
  float m = fmaxf(fmaxf(v.x,v.y),fmaxf(v.z,v.w));
  #pragma unroll
  for (int off=32;off;off>>=1) m = fmaxf(m, __shfl_down(m,off));
  if ((tid&63)==0) red[tid>>6]=m;
  __syncthreads();
  if (tid==0){ float mm=red[0]; for (int i=1;i<16;i++) mm=fmaxf(mm,red[i]); gsh[0]=mm; }
  __syncthreads();
  float gm = gsh[0];
  float e0=__expf(v.x-gm), e1=__expf(v.y-gm), e2=__expf(v.z-gm), e3=__expf(v.w-gm);
  float s = e0+e1+e2+e3;
  #pragma unroll
  for (int off=32;off;off>>=1) s += __shfl_down(s,off);
  if ((tid&63)==0) red[tid>>6]=s;
  __syncthreads();
  if (tid==0){ float ss=0; for (int i=0;i<16;i++) ss+=red[i]; gsh[1]=ss; }
  __syncthreads();
  float inv = 1.0f/gsh[1];
  ((float4*)wsm)[tid] = make_float4(e0*inv,e1*inv,e2*inv,e3*inv);
}

// ---- MLP emissions: feats = W2 relu(w_s*(W1 h) + b1) + b2
__global__ __launch_bounds__(256) void mlp_feats(const float* __restrict__ h1, const float* __restrict__ wsm,
                                                 const float* __restrict__ W1, const float* __restrict__ b1,
                                                 const float* __restrict__ W2, const float* __restrict__ b2,
                                                 float* __restrict__ feats){
  __shared__ float4 hsl[8*128];
  __shared__ float rl[8][256];
  __shared__ float wloc[8];
  int tid=threadIdx.x;
  int s0=blockIdx.x*8;
  const float4* h4=(const float4*)(h1 + (size_t)s0*HIDD);
  for (int i=tid;i<8*128;i+=256) hsl[i]=h4[i];
  if (tid<8) wloc[tid]=wsm[s0+tid];
  __syncthreads();
  const float4* w1=(const float4*)(W1 + (size_t)tid*HIDD);
  float acc[8];
  #pragma unroll
  for (int r=0;r<8;r++) acc[r]=0.f;
  for (int k4=0;k4<128;k4++){
    float4 wv=w1[k4];
    #pragma unroll
    for (int r=0;r<8;r++){
      float4 xv=hsl[r*128+k4];
      acc[r]=fmaf(wv.x,xv.x,fmaf(wv.y,xv.y,fmaf(wv.z,xv.z,fmaf(wv.w,xv.w,acc[r]))));
    }
  }
  float bb=b1[tid];
  #pragma unroll
  for (int r=0;r<8;r++) rl[r][tid]=fmaxf(fmaf(acc[r],wloc[r],bb),0.f);
  __syncthreads();
  if (tid < 96){
    int r=tid/12, t=tid-12*(tid/12);
    const float* w2=W2 + t*256;
    float a=b2[t];
    for (int m2=0;m2<256;m2++) a += w2[m2]*rl[r][m2];
    feats[(size_t)(s0+r)*TT + t]=a;
  }
}

// ---- CRF parallel scan: chunk products of M_t[i][j] = trans[i][j] + feats[t][i]
__global__ __launch_bounds__(192) void crf_chunks(const float* __restrict__ feats,
                                                  const float* __restrict__ trans,
                                                  float* __restrict__ Cmat){
  int c = blockIdx.x;
  int tid = threadIdx.x;
  __shared__ float trs[144];
  __shared__ float cur[144];
  __shared__ float ft[12];
  if (tid<144) trs[tid]=trans[tid];
  __syncthreads();
  int t0 = c*CL;
  int i = tid/12, jcol = tid - 12*(tid/12);
  float cv = 0.f;
  if (tid<144) cv = trs[tid] + feats[(size_t)t0*TT + i];
  for (int s=t0+1; s<t0+CL; ++s){
    if (tid<144) cur[tid]=cv;
    if (tid<12)  ft[tid] = feats[(size_t)s*TT+tid];
    __syncthreads();
    if (tid<144){
      float v[12]; float m=-3.0e38f;
      #pragma unroll
      for (int k=0;k<12;k++){ v[k] = trs[i*12+k] + cur[k*12+jcol]; m=fmaxf(m,v[k]); }
      float ss=0.f;
      #pragma unroll
      for (int k=0;k<12;k++) ss += __expf(v[k]-m);
      cv = ft[i] + m + __logf(ss);
    }
    __syncthreads();
  }
  if (tid<144) Cmat[(size_t)c*144 + tid] = cv;
}

__global__ __launch_bounds__(256) void crf_combine(const float* __restrict__ Cmat,
                                                   const float* __restrict__ trans,
                                                   const float* __restrict__ feats,
                                                   const int* __restrict__ tags,
                                                   float* __restrict__ out){
  __shared__ float trb[144];
  __shared__ float fv[12];
  __shared__ float Csh[144];
  __shared__ float red[4];
  __shared__ float goldsh;
  int tid=threadIdx.x;
  if (tid<144) trb[tid]=trans[tid];
  __syncthreads();
  float gacc=0.f;
  for (int s=tid; s<SEQ; s+=256){
    int tg = tags[s];
    int pv = s ? tags[s-1] : START_TAG;
    gacc += feats[(size_t)s*TT+tg] + trb[tg*12+pv];
  }
  #pragma unroll
  for (int off=32;off;off>>=1) gacc += __shfl_down(gacc,off);
  if ((tid&63)==0) red[tid>>6]=gacc;
  __syncthreads();
  if (tid==0) goldsh = red[0]+red[1]+red[2]+red[3] + trb[STOP_TAG*12 + tags[SEQ-1]];
  if (tid<12) fv[tid] = (tid==START_TAG) ? 0.f : NEGV;
  __syncthreads();
  for (int cc=0; cc<NC; ++cc){
    if (tid<144) Csh[tid] = Cmat[(size_t)cc*144+tid];
    __syncthreads();
    float nf=0.f;
    if (tid<12){
      float v[12]; float m=-3.0e38f;
      #pragma unroll
      for (int k=0;k<12;k++){ v[k]=Csh[tid*12+k]+fv[k]; m=fmaxf(m,v[k]); }
      float ss=0.f;
      #pragma unroll
      for (int k=0;k<12;k++) ss+=__expf(v[k]-m);
      nf = m+__logf(ss);
    }
    __syncthreads();
    if (tid<12) fv[tid]=nf;
    __syncthreads();
  }
  if (tid==0){
    float v[12]; float m=-3.0e38f;
    #pragma unroll
    for (int k=0;k<12;k++){ v[k]=fv[k]+trb[STOP_TAG*12+k]; m=fmaxf(m,v[k]); }
    float ss=0.f;
    #pragma unroll
    for (int k=0;k<12;k++) ss+=__expf(v[k]-m);
    out[0] = m + __logf(ss) - goldsh;
  }
}

extern "C" void kernel_launch(void* const* d_in, const int* in_sizes, int n_in,
                              void* d_out, int out_size, void* d_ws, size_t ws_size,
                              hipStream_t stream){
  const int*   sent  = (const int*)d_in[0];
  const int*   tags  = (const int*)d_in[1];
  const float* embed = (const float*)d_in[2];
  const float* W0ih  = (const float*)d_in[3];
  const float* W0hh  = (const float*)d_in[4];
  const float* b0    = (const float*)d_in[5];
  const float* W1ih  = (const float*)d_in[6];
  const float* W1hh  = (const float*)d_in[7];
  const float* b1l   = (const float*)d_in[8];
  const float* Wa    = (const float*)d_in[9];
  const float* ba    = (const float*)d_in[10];
  const float* vctx  = (const float*)d_in[11];
  const float* W1m   = (const float*)d_in[12];
  const float* b1m   = (const float*)d_in[13];
  const float* W2m   = (const float*)d_in[14];
  const float* b2m   = (const float*)d_in[15];
  const float* trans = (const float*)d_in[16];
  float* out = (float*)d_out;

  float* ws = (float*)d_ws;
  size_t off = 0;
  float*  x     = ws + off;            off += (size_t)SEQ*DIM;       // 4 MB
  float4* WihT0 = (float4*)(ws + off); off += (size_t)2*64*G4*4;     // 2 MB
  float4* WihT1 = (float4*)(ws + off); off += (size_t)2*128*G4*4;    // 4 MB
  uint4*  WhhB0 = (uint4*)(ws + off);  off += (size_t)2*32*G4*4;     // 1 MB
  uint4*  WhhB1 = (uint4*)(ws + off);  off += (size_t)2*32*G4*4;     // 1 MB
  float*  h0    = ws + off;            off += (size_t)SEQ*HIDD;      // 8 MB
  float*  h1    = ws + off;            off += (size_t)SEQ*HIDD;      // 8 MB
  float*  scores= ws + off;            off += SEQ;
  float*  wsm   = ws + off;            off += SEQ;
  float*  feats = ws + off;            off += (size_t)SEQ*TT;
  float*  Cmat  = ws + off;            off += (size_t)NC*144;
  u64*    exch  = (u64*)(ws + off);    off += (size_t)2*2048*2;      // 2 layers * 2048 u64
  float*  P     = ws + off;            off += (size_t)2*SEQ*G4;      // 32 MB

  const int scanLds = 32*256*16 + 64*16 + 256*4;   // 133120 B
  hipFuncSetAttribute((const void*)lstm_scan7, hipFuncAttributeMaxDynamicSharedMemorySize, scanLds);

  pack_wih<256><<<dim3(2*64*G4/256), dim3(256), 0, stream>>>(W0ih, WihT0);
  pack_wih<512><<<dim3(2*128*G4/256), dim3(256), 0, stream>>>(W1ih, WihT1);
  pack_whh<<<dim3(2*32*G4/256), dim3(256), 0, stream>>>(W0hh, WhhB0);
  pack_whh<<<dim3(2*32*G4/256), dim3(256), 0, stream>>>(W1hh, WhhB1);

  gather_embed<<<dim3(SEQ), dim3(64), 0, stream>>>(sent, embed, (float4*)x);

  inproj<256><<<dim3(2048), dim3(256), 0, stream>>>(x, WihT0, b0, P);
  lstm_scan7<<<dim3(2*NG), dim3(256), scanLds, stream>>>(WhhB0, P, h0, exch);
  inproj<512><<<dim3(2048), dim3(256), 0, stream>>>(h0, WihT1, b1l, P);
  lstm_scan7<<<dim3(2*NG), dim3(256), scanLds, stream>>>(WhhB1, P, h1, exch + 2048);

  attn_scores<<<dim3(512), dim3(128), 0, stream>>>(h1, Wa, ba, vctx, scores);
  softmax_seq<<<dim3(1), dim3(1024), 0, stream>>>(scores, wsm);
  mlp_feats<<<dim3(512), dim3(256), 0, stream>>>(h1, wsm, W1m, b1m, W2m, b2m, feats);
  crf_chunks<<<dim3(NC), dim3(192), 0, stream>>>(feats, trans, Cmat);
  crf_combine<<<dim3(1), dim3(256), 0, stream>>>(Cmat, trans, feats, tags, out);
}

// Round 10
// 21645.860 us; speedup vs baseline: 1.3029x; 1.1501x over previous
//
#include <hip/hip_runtime.h>
#include <math.h>

#define SEQ 4096
#define DIM 256
#define HIDD 512
#define HH 256
#define G4 1024      // 4*H
#define TT 12
#define AA 128
#define START_TAG 10
#define STOP_TAG 11
#define NEGV (-10000.0f)
#define NG 4         // workgroups per direction
#define SL 64        // h-slice per workgroup (256/NG)
#define NC 64        // CRF chunks
#define CL 64        // CRF chunk length

typedef unsigned int u32;
typedef unsigned long long u64;

__device__ __forceinline__ float sigf(float x){ return 1.0f/(1.0f+__expf(-x)); }
__device__ __forceinline__ float tanhfast(float x){ float e=__expf(2.f*x); return (e-1.f)/(e+1.f); }

// LDS-only barrier: do NOT drain vmcnt (ring stores / P prefetch keep flying).
__device__ __forceinline__ void lds_barrier(){
  asm volatile("s_waitcnt lgkmcnt(0)" ::: "memory");
  __builtin_amdgcn_sched_barrier(0);
  __builtin_amdgcn_s_barrier();
  __builtin_amdgcn_sched_barrier(0);
}

__device__ __forceinline__ unsigned short f2bf(float f){
  u32 u = __float_as_uint(f);
  u32 r = u + 0x7fffu + ((u>>16)&1u);   // RNE
  return (unsigned short)(r>>16);
}

// ---- prep: transpose-pack Wih (2,G4,K) f32 -> float4 [2][K/4][G4] (coalesced j)
template<int K>
__global__ __launch_bounds__(256) void pack_wih(const float* __restrict__ src, float4* __restrict__ dst){
  const int KQ = K/4;
  int idx = blockIdx.x*256 + threadIdx.x;        // 2*KQ*G4 total
  int j = idx & (G4-1);
  int r = idx >> 10;
  int k4 = r % KQ;
  int d  = r / KQ;
  const float* p = src + ((size_t)(d*G4 + j))*K + k4*4;
  dst[idx] = make_float4(p[0],p[1],p[2],p[3]);
}

// ---- prep: pack Whh (2,G4,HH) f32 -> bf16 pairs, uint4 [2][32][G4] (k8-major, coalesced j)
__global__ __launch_bounds__(256) void pack_whh(const float* __restrict__ src, uint4* __restrict__ dst){
  int idx = blockIdx.x*256 + threadIdx.x;        // 65536 total
  int j  = idx & (G4-1);
  int k8 = (idx>>10) & 31;
  int d  = idx >> 15;
  const float* p = src + ((size_t)(d*G4 + j))*HH + k8*8;
  uint4 v;
  v.x = (u32)f2bf(p[0]) | ((u32)f2bf(p[1])<<16);
  v.y = (u32)f2bf(p[2]) | ((u32)f2bf(p[3])<<16);
  v.z = (u32)f2bf(p[4]) | ((u32)f2bf(p[5])<<16);
  v.w = (u32)f2bf(p[6]) | ((u32)f2bf(p[7])<<16);
  dst[idx] = v;
}

__global__ __launch_bounds__(64) void gather_embed(const int* __restrict__ sent, const float* __restrict__ embed,
                                                   float4* __restrict__ x4){
  int s = blockIdx.x;
  const float4* src = (const float4*)(embed + (size_t)sent[s]*DIM);
  x4[(size_t)s*64 + threadIdx.x] = src[threadIdx.x];
}

// ---- input projection: P[d][t][j] = b[d][j] + sum_k in[t][k]*Wih[d][j][k]
template<int K>
__global__ __launch_bounds__(256) void inproj(const float* __restrict__ in, const float4* __restrict__ WT4,
                                              const float* __restrict__ bias, float* __restrict__ P){
  const int KQ = K/4;
  int bid = blockIdx.x;             // 2 * 256 * 4 blocks
  int jt = bid & 3;
  int st = (bid>>2) & 255;
  int d  = bid >> 10;
  __shared__ float4 xs[16*KQ];
  int tid = threadIdx.x;
  int s0 = st*16;
  const float4* in4 = (const float4*)(in + (size_t)s0*K);
  for (int i=tid; i<16*KQ; i+=256) xs[i] = in4[i];
  __syncthreads();
  int j = jt*256 + tid;
  float b = bias[d*G4 + j];
  float acc[16];
  #pragma unroll
  for (int r=0;r<16;r++) acc[r]=b;
  const float4* w = WT4 + (size_t)d*KQ*G4 + j;
  for (int k4=0;k4<KQ;k4++){
    float4 wv = w[(size_t)k4*G4];
    #pragma unroll
    for (int r=0;r<16;r++){
      float4 xv = xs[r*KQ + k4];
      acc[r] = fmaf(wv.x,xv.x, fmaf(wv.y,xv.y, fmaf(wv.z,xv.z, fmaf(wv.w,xv.w, acc[r]))));
    }
  }
  #pragma unroll
  for (int r=0;r<16;r++)
    P[((size_t)d*SEQ + (s0+r))*G4 + j] = acc[r];
}

// ---- LSTM scan v8: LDS weights (proven R9) + restructured exchange:
//      raw LDS-only barriers (no vmcnt drain), top-of-step poll for the
//      PREVIOUS step's slot overlapped with own-slice partial dot, own h
//      slice written to LDS directly (no LLC round trip).
#define QDOT(i,A) { uint4 qv = wl[(i)*256 + tid]; \
  float4 ha = hs4[2*(i)]; float4 hb = hs4[2*(i)+1]; \
  A = fmaf(__uint_as_float(qv.x<<16),           ha.x, A); \
  A = fmaf(__uint_as_float(qv.x & 0xffff0000u), ha.y, A); \
  A = fmaf(__uint_as_float(qv.y<<16),           ha.z, A); \
  A = fmaf(__uint_as_float(qv.y & 0xffff0000u), ha.w, A); \
  A = fmaf(__uint_as_float(qv.z<<16),           hb.x, A); \
  A = fmaf(__uint_as_float(qv.z & 0xffff0000u), hb.y, A); \
  A = fmaf(__uint_as_float(qv.w<<16),           hb.z, A); \
  A = fmaf(__uint_as_float(qv.w & 0xffff0000u), hb.w, A); }

__global__ __launch_bounds__(256,1) void lstm_scan8(const uint4* __restrict__ WhhB,
                                                    const float* __restrict__ P,
                                                    float* __restrict__ hout,
                                                    u64* __restrict__ exbase){
  extern __shared__ uint4 smem[];
  uint4*  wl  = smem;                         // 32*256 uint4 = 128 KB
  float4* hs4 = (float4*)(wl + 32*256);       // 64 float4 (h_{t-1}, 256 f32)
  float*  gv  = (float*)(hs4 + 64);           // 256 f32 gate pre-activations
  float*  hs  = (float*)hs4;

  const int d = blockIdx.x & 1;
  const int g = blockIdx.x >> 1;
  const int tid = threadIdx.x;
  const int q  = tid >> 6;              // gate index (i,f,g,o)
  const int jj = tid & 63;              // index within h-slice
  const int j  = q*256 + g*SL + jj;     // global gate-row
  const bool remote = (tid>>6) != g;    // this thread's h element lives in another WG

  // stage weights into LDS once: wl[k8*256 + tid] = WhhB[d][k8][j]
  const uint4* wsrc = WhhB + (size_t)d*32*G4 + j;
  #pragma unroll 4
  for (int k8=0;k8<32;k8++) wl[k8*256 + tid] = wsrc[(size_t)k8*G4];

  hs[tid] = 0.f;
  float c = 0.f;
  const float* Pd = P + (size_t)d*SEQ*G4;
  const int t0 = d ? SEQ-1 : 0;
  float pcur = Pd[(size_t)t0*G4 + j];
  u64* exd = exbase + (size_t)d*1024;   // [4 slots][256]
  __syncthreads();

  for (int tt=0; tt<SEQ; ++tt){
    const int t  = d ? (SEQ-1-tt) : tt;
    const int tn = d ? (t>0 ? t-1 : 0) : (t<SEQ-1 ? t+1 : t);
    float pnext = Pd[(size_t)tn*G4 + j];      // prefetch next step's P

    // ---- poll (previous step's slot) issued early, overlapped with partial dot
    u64* expl = exd + (size_t)((tt+3)&3)*256;   // slot (tt-1)&3
    const u64 want = (u64)(u32)tt;              // tag stored at step tt-1
    u64 v = 0;
    if (tt>0 && remote)
      v = __hip_atomic_load(&expl[tid], __ATOMIC_RELAXED, __HIP_MEMORY_SCOPE_AGENT);

    // ---- partial dot over OWN k8 blocks [8g, 8g+8) (own slice fresh in LDS)
    float acc0 = pcur, acc1 = 0.f, acc2 = 0.f, acc3 = 0.f;
    {
      const int kb = g*8;
      QDOT(kb+0,acc0) QDOT(kb+1,acc1) QDOT(kb+2,acc2) QDOT(kb+3,acc3)
      QDOT(kb+4,acc0) QDOT(kb+5,acc1) QDOT(kb+6,acc2) QDOT(kb+7,acc3)
    }

    if (tt>0 && remote){
      while ((v>>32) != want)
        v = __hip_atomic_load(&expl[tid], __ATOMIC_RELAXED, __HIP_MEMORY_SCOPE_AGENT);
      hs[tid] = __uint_as_float((u32)v);
    }
    lds_barrier();                              // remote slices now in hs

    // ---- remaining 24 k8 blocks (3 remote groups; kb wave-uniform)
    #pragma unroll
    for (int rg=1; rg<4; ++rg){
      const int kb = ((g+rg)&3)*8;
      QDOT(kb+0,acc0) QDOT(kb+1,acc1) QDOT(kb+2,acc2) QDOT(kb+3,acc3)
      QDOT(kb+4,acc0) QDOT(kb+5,acc1) QDOT(kb+6,acc2) QDOT(kb+7,acc3)
    }
    gv[tid] = (acc0+acc1)+(acc2+acc3);
    lds_barrier();

    // ---- activation: own slice -> LDS (local), hout (plain), ring (agent)
    u64* exst = exd + (size_t)(tt&3)*256;
    if (tid < SL){
      float gi = sigf(gv[tid]);
      float gf = sigf(gv[64 + tid]);
      float gg = tanhfast(gv[128 + tid]);
      float go = sigf(gv[192 + tid]);
      c = gf*c + gi*gg;
      float h = go*tanhfast(c);
      hs[g*SL + tid] = h;                                  // local LDS write
      u64 pk = ((u64)(u32)(tt+1) << 32) | (u64)__float_as_uint(h);
      __hip_atomic_store(&exst[g*SL + tid], pk, __ATOMIC_RELAXED, __HIP_MEMORY_SCOPE_AGENT);
      hout[(size_t)t*HIDD + d*HH + g*SL + tid] = h;        // for later kernels
    }
    pcur = pnext;
    lds_barrier();                              // own slice visible for next partial dot
  }
}

// ---- attention scores: scores[s] = v . tanh(Wa h[s] + ba)
__global__ __launch_bounds__(128) void attn_scores(const float* __restrict__ h1, const float* __restrict__ Wa,
                                                   const float* __restrict__ ba, const float* __restrict__ vctx,
                                                   float* __restrict__ scores){
  __shared__ float4 hsl[8*128];
  __shared__ float red[2];
  int tid = threadIdx.x;
  int s0 = blockIdx.x*8;
  const float4* h4 = (const float4*)(h1 + (size_t)s0*HIDD);
  for (int i=tid;i<8*128;i+=128) hsl[i]=h4[i];
  __syncthreads();
  const float4* wa = (const float4*)(Wa + (size_t)tid*HIDD);
  float acc[8];
  #pragma unroll
  for (int r=0;r<8;r++) acc[r]=0.f;
  for (int k4=0;k4<128;k4++){
    float4 wv = wa[k4];
    #pragma unroll
    for (int r=0;r<8;r++){
      float4 xv = hsl[r*128+k4];
      acc[r] = fmaf(wv.x,xv.x,fmaf(wv.y,xv.y,fmaf(wv.z,xv.z,fmaf(wv.w,xv.w,acc[r]))));
    }
  }
  float myb = ba[tid], myv = vctx[tid];
  for (int r=0;r<8;r++){
    float p = tanhf(acc[r]+myb)*myv;
    #pragma unroll
    for (int off=32;off;off>>=1) p += __shfl_down(p, off);
    if ((tid&63)==0) red[tid>>6]=p;
    __syncthreads();
    if (tid==0) scores[s0+r] = red[0]+red[1];
    __syncthreads();
  }
}

__global__ __launch_bounds__(1024) void softmax_seq(const float* __restrict__ scores, float* __restrict__ wsm){
  __shared__ float red[16];
  __shared__ float gsh[2];
  int tid=threadIdx.x;
  float4 v = ((const float4*)scores)[tid];
  float m = fmaxf(fmaxf(v.x,v.y),fmaxf(v.z,v.w));
  #pragma unroll
  for (int off=32;off;off>>=1) m = fmaxf(m, __shfl_down(m,off));
  if ((tid&63)==0) red[tid>>6]=m;
  __syncthreads();
  if (tid==0){ float mm=red[0]; for (int i=1;i<16;i++) mm=fmaxf(mm,red[i]); gsh[0]=mm; }
  __syncthreads();
  float gm = gsh[0];
  float e0=__expf(v.x-gm), e1=__expf(v.y-gm), e2=__expf(v.z-gm), e3=__expf(v.w-gm);
  float s = e0+e1+e2+e3;
  #pragma unroll
  for (int off=32;off;off>>=1) s += __shfl_down(s,off);
  if ((tid&63)==0) red[tid>>6]=s;
  __syncthreads();
  if (tid==0){ float ss=0; for (int i=0;i<16;i++) ss+=red[i]; gsh[1]=ss; }
  __syncthreads();
  float inv = 1.0f/gsh[1];
  ((float4*)wsm)[tid] = make_float4(e0*inv,e1*inv,e2*inv,e3*inv);
}

// ---- MLP emissions: feats = W2 relu(w_s*(W1 h) + b1) + b2
__global__ __launch_bounds__(256) void mlp_feats(const float* __restrict__ h1, const float* __restrict__ wsm,
                                                 const float* __restrict__ W1, const float* __restrict__ b1,
                                                 const float* __restrict__ W2, const float* __restrict__ b2,
                                                 float* __restrict__ feats){
  __shared__ float4 hsl[8*128];
  __shared__ float rl[8][256];
  __shared__ float wloc[8];
  int tid=threadIdx.x;
  int s0=blockIdx.x*8;
  const float4* h4=(const float4*)(h1 + (size_t)s0*HIDD);
  for (int i=tid;i<8*128;i+=256) hsl[i]=h4[i];
  if (tid<8) wloc[tid]=wsm[s0+tid];
  __syncthreads();
  const float4* w1=(const float4*)(W1 + (size_t)tid*HIDD);
  float acc[8];
  #pragma unroll
  for (int r=0;r<8;r++) acc[r]=0.f;
  for (int k4=0;k4<128;k4++){
    float4 wv=w1[k4];
    #pragma unroll
    for (int r=0;r<8;r++){
      float4 xv=hsl[r*128+k4];
      acc[r]=fmaf(wv.x,xv.x,fmaf(wv.y,xv.y,fmaf(wv.z,xv.z,fmaf(wv.w,xv.w,acc[r]))));
    }
  }
  float bb=b1[tid];
  #pragma unroll
  for (int r=0;r<8;r++) rl[r][tid]=fmaxf(fmaf(acc[r],wloc[r],bb),0.f);
  __syncthreads();
  if (tid < 96){
    int r=tid/12, t=tid-12*(tid/12);
    const float* w2=W2 + t*256;
    float a=b2[t];
    for (int m2=0;m2<256;m2++) a += w2[m2]*rl[r][m2];
    feats[(size_t)(s0+r)*TT + t]=a;
  }
}

// ---- CRF parallel scan: chunk products of M_t[i][j] = trans[i][j] + feats[t][i]
__global__ __launch_bounds__(192) void crf_chunks(const float* __restrict__ feats,
                                                  const float* __restrict__ trans,
                                                  float* __restrict__ Cmat){
  int c = blockIdx.x;
  int tid = threadIdx.x;
  __shared__ float trs[144];
  __shared__ float cur[144];
  __shared__ float ft[12];
  if (tid<144) trs[tid]=trans[tid];
  __syncthreads();
  int t0 = c*CL;
  int i = tid/12, jcol = tid - 12*(tid/12);
  float cv = 0.f;
  if (tid<144) cv = trs[tid] + feats[(size_t)t0*TT + i];
  for (int s=t0+1; s<t0+CL; ++s){
    if (tid<144) cur[tid]=cv;
    if (tid<12)  ft[tid] = feats[(size_t)s*TT+tid];
    __syncthreads();
    if (tid<144){
      float v[12]; float m=-3.0e38f;
      #pragma unroll
      for (int k=0;k<12;k++){ v[k] = trs[i*12+k] + cur[k*12+jcol]; m=fmaxf(m,v[k]); }
      float ss=0.f;
      #pragma unroll
      for (int k=0;k<12;k++) ss += __expf(v[k]-m);
      cv = ft[i] + m + __logf(ss);
    }
    __syncthreads();
  }
  if (tid<144) Cmat[(size_t)c*144 + tid] = cv;
}

__global__ __launch_bounds__(256) void crf_combine(const float* __restrict__ Cmat,
                                                   const float* __restrict__ trans,
                                                   const float* __restrict__ feats,
                                                   const int* __restrict__ tags,
                                                   float* __restrict__ out){
  __shared__ float trb[144];
  __shared__ float fv[12];
  __shared__ float Csh[144];
  __shared__ float red[4];
  __shared__ float goldsh;
  int tid=threadIdx.x;
  if (tid<144) trb[tid]=trans[tid];
  __syncthreads();
  float gacc=0.f;
  for (int s=tid; s<SEQ; s+=256){
    int tg = tags[s];
    int pv = s ? tags[s-1] : START_TAG;
    gacc += feats[(size_t)s*TT+tg] + trb[tg*12+pv];
  }
  #pragma unroll
  for (int off=32;off;off>>=1) gacc += __shfl_down(gacc,off);
  if ((tid&63)==0) red[tid>>6]=gacc;
  __syncthreads();
  if (tid==0) goldsh = red[0]+red[1]+red[2]+red[3] + trb[STOP_TAG*12 + tags[SEQ-1]];
  if (tid<12) fv[tid] = (tid==START_TAG) ? 0.f : NEGV;
  __syncthreads();
  for (int cc=0; cc<NC; ++cc){
    if (tid<144) Csh[tid] = Cmat[(size_t)cc*144+tid];
    __syncthreads();
    float nf=0.f;
    if (tid<12){
      float v[12]; float m=-3.0e38f;
      #pragma unroll
      for (int k=0;k<12;k++){ v[k]=Csh[tid*12+k]+fv[k]; m=fmaxf(m,v[k]); }
      float ss=0.f;
      #pragma unroll
      for (int k=0;k<12;k++) ss+=__expf(v[k]-m);
      nf = m+__logf(ss);
    }
    __syncthreads();
    if (tid<12) fv[tid]=nf;
    __syncthreads();
  }
  if (tid==0){
    float v[12]; float m=-3.0e38f;
    #pragma unroll
    for (int k=0;k<12;k++){ v[k]=fv[k]+trb[STOP_TAG*12+k]; m=fmaxf(m,v[k]); }
    float ss=0.f;
    #pragma unroll
    for (int k=0;k<12;k++) ss+=__expf(v[k]-m);
    out[0] = m + __logf(ss) - goldsh;
  }
}

extern "C" void kernel_launch(void* const* d_in, const int* in_sizes, int n_in,
                              void* d_out, int out_size, void* d_ws, size_t ws_size,
                              hipStream_t stream){
  const int*   sent  = (const int*)d_in[0];
  const int*   tags  = (const int*)d_in[1];
  const float* embed = (const float*)d_in[2];
  const float* W0ih  = (const float*)d_in[3];
  const float* W0hh  = (const float*)d_in[4];
  const float* b0    = (const float*)d_in[5];
  const float* W1ih  = (const float*)d_in[6];
  const float* W1hh  = (const float*)d_in[7];
  const float* b1l   = (const float*)d_in[8];
  const float* Wa    = (const float*)d_in[9];
  const float* ba    = (const float*)d_in[10];
  const float* vctx  = (const float*)d_in[11];
  const float* W1m   = (const float*)d_in[12];
  const float* b1m   = (const float*)d_in[13];
  const float* W2m   = (const float*)d_in[14];
  const float* b2m   = (const float*)d_in[15];
  const float* trans = (const float*)d_in[16];
  float* out = (float*)d_out;

  float* ws = (float*)d_ws;
  size_t off = 0;
  float*  x     = ws + off;            off += (size_t)SEQ*DIM;       // 4 MB
  float4* WihT0 = (float4*)(ws + off); off += (size_t)2*64*G4*4;     // 2 MB
  float4* WihT1 = (float4*)(ws + off); off += (size_t)2*128*G4*4;    // 4 MB
  uint4*  WhhB0 = (uint4*)(ws + off);  off += (size_t)2*32*G4*4;     // 1 MB
  uint4*  WhhB1 = (uint4*)(ws + off);  off += (size_t)2*32*G4*4;     // 1 MB
  float*  h0    = ws + off;            off += (size_t)SEQ*HIDD;      // 8 MB
  float*  h1    = ws + off;            off += (size_t)SEQ*HIDD;      // 8 MB
  float*  scores= ws + off;            off += SEQ;
  float*  wsm   = ws + off;            off += SEQ;
  float*  feats = ws + off;            off += (size_t)SEQ*TT;
  float*  Cmat  = ws + off;            off += (size_t)NC*144;
  u64*    exch  = (u64*)(ws + off);    off += (size_t)2*2048*2;      // 2 layers * 2048 u64
  float*  P     = ws + off;            off += (size_t)2*SEQ*G4;      // 32 MB

  const int scanLds = 32*256*16 + 64*16 + 256*4;   // 133120 B
  hipFuncSetAttribute((const void*)lstm_scan8, hipFuncAttributeMaxDynamicSharedMemorySize, scanLds);

  pack_wih<256><<<dim3(2*64*G4/256), dim3(256), 0, stream>>>(W0ih, WihT0);
  pack_wih<512><<<dim3(2*128*G4/256), dim3(256), 0, stream>>>(W1ih, WihT1);
  pack_whh<<<dim3(2*32*G4/256), dim3(256), 0, stream>>>(W0hh, WhhB0);
  pack_whh<<<dim3(2*32*G4/256), dim3(256), 0, stream>>>(W1hh, WhhB1);

  gather_embed<<<dim3(SEQ), dim3(64), 0, stream>>>(sent, embed, (float4*)x);

  inproj<256><<<dim3(2048), dim3(256), 0, stream>>>(x, WihT0, b0, P);
  lstm_scan8<<<dim3(2*NG), dim3(256), scanLds, stream>>>(WhhB0, P, h0, exch);
  inproj<512><<<dim3(2048), dim3(256), 0, stream>>>(h0, WihT1, b1l, P);
  lstm_scan8<<<dim3(2*NG), dim3(256), scanLds, stream>>>(WhhB1, P, h1, exch + 2048);

  attn_scores<<<dim3(512), dim3(128), 0, stream>>>(h1, Wa, ba, vctx, scores);
  softmax_seq<<<dim3(1), dim3(1024), 0, stream>>>(scores, wsm);
  mlp_feats<<<dim3(512), dim3(256), 0, stream>>>(h1, wsm, W1m, b1m, W2m, b2m, feats);
  crf_chunks<<<dim3(NC), dim3(192), 0, stream>>>(feats, trans, Cmat);
  crf_combine<<<dim3(1), dim3(256), 0, stream>>>(Cmat, trans, feats, tags, out);
}